// Round 1
// baseline (209.548 us; speedup 1.0000x reference)
//
#include <hip/hip_runtime.h>
#include <cstddef>
#include <cstdint>

#define B_  4
#define N_  1024
#define D_  1024
#define H_  16
#define DH  64
#define M_  4096   // B_*N_

typedef __attribute__((ext_vector_type(4))) float   f32x4;
typedef __attribute__((ext_vector_type(8))) __bf16  bf16x8;

#define MFMA(a, b, c) __builtin_amdgcn_mfma_f32_16x16x32_bf16((a), (b), (c), 0, 0, 0)
#define GLDS(gp, lp) __builtin_amdgcn_global_load_lds( \
    (__attribute__((address_space(1))) void*)(gp),     \
    (__attribute__((address_space(3))) void*)(lp), 16, 0, 0)

// ---------------------------------------------------------------------------
// convert: fp32 -> bf16 for x (4Mi) and Wq/Wk/Wv/Wc (4x1Mi). [verified R3]
// ---------------------------------------------------------------------------
__global__ __launch_bounds__(256) void convert_k(
    const float* __restrict__ x,  const float* __restrict__ Wq,
    const float* __restrict__ Wk, const float* __restrict__ Wv,
    const float* __restrict__ Wc,
    __bf16* __restrict__ xb, __bf16* __restrict__ wqkvb,
    __bf16* __restrict__ wcb)
{
    const unsigned u = blockIdx.x * 256u + threadIdx.x;
    const unsigned e = u * 8u;
    const float* src;
    __bf16* dst;
    if (e < 4194304u) { src = x + e; dst = xb + e; }
    else {
        const unsigned t2 = e - 4194304u;
        const unsigned wsel = t2 >> 20;
        const unsigned wo = t2 & 1048575u;
        src = (wsel == 0 ? Wq : wsel == 1 ? Wk : wsel == 2 ? Wv : Wc) + wo;
        dst = (wsel < 3 ? wqkvb + (size_t)wsel * 1048576u : wcb) + wo;
    }
    const float4 f0 = *(const float4*)(src);
    const float4 f1 = *(const float4*)(src + 4);
    bf16x8 r;
    r[0] = (__bf16)f0.x; r[1] = (__bf16)f0.y; r[2] = (__bf16)f0.z; r[3] = (__bf16)f0.w;
    r[4] = (__bf16)f1.x; r[5] = (__bf16)f1.y; r[6] = (__bf16)f1.z; r[7] = (__bf16)f1.w;
    *(bf16x8*)dst = r;
}

// ---------------------------------------------------------------------------
// QKV GEMM — R11: 128x128/BK=32 structure re-piped as 3-deep LDS ring with
// distance-2 prefetch, raw s_barrier + counted vmcnt (T3/T4-min). Theory:
// R10 counters showed MfmaUtil 16.5 / VALUBusy 8.8 / HBM 13.6% = latency-
// bound on the per-K-step vmcnt(0) drain inside __syncthreads. One barrier
// per K-step; loads for tile t+2 issued right after the tile-t barrier.
// Hazards: top-of-t barrier (a) publishes tile-t LDS (each wave waited its
// own vmcnt(4) first => oldest 4 loads = tile t landed), (b) proves all
// waves drained iter-(t-1) ds_reads (lgkmcnt before their MFMAs), so
// staging into buf[(t+2)%3] = buf[(t-1)%3] is safe. Epilogues unchanged
// [verified R6-R10]: z=0,1 heads scatter; z=2 swapped-operand V^T.
// ---------------------------------------------------------------------------
__global__ __launch_bounds__(256, 3) void gemm_qkv(
    const __bf16* __restrict__ xb, const __bf16* __restrict__ Wb,
    const float* __restrict__ bq, const float* __restrict__ bk,
    const float* __restrict__ bv,
    __bf16* __restrict__ qk_out, __bf16* __restrict__ vT)
{
    __shared__ __bf16 As[3 * 4096];   // 3 x 128x32 bf16 ring (24KB)
    __shared__ __bf16 Bs[3 * 4096];   // 24KB -> 48KB total, 3 blocks/CU

    const int tid  = threadIdx.x;
    const int w    = tid >> 6;
    const int lane = tid & 63;
    const int quad = lane >> 4;
    const int l15  = lane & 15;
    const int wr   = w >> 1, wc = w & 1;

    const int z  = blockIdx.z;
    const bool VT = (z == 2);

    int m0, n0;
    if (VT) { m0 = blockIdx.x * 128; n0 = blockIdx.y * 128; }   // m0 over e, n0 over m
    else    { m0 = blockIdx.y * 128; n0 = blockIdx.x * 128; }

    const __bf16* Ap = VT ? (Wb + (size_t)2 * D_ * D_) : xb;
    const __bf16* Bp = VT ? xb : (Wb + (size_t)z * D_ * D_);

    // staging chunk decode [verified R3-R8]: c -> row (c>>6)*16+(c&15), octet (c>>4)&3
    const int c1 = w * 128 + lane, c2 = c1 + 64;
    const size_t aoff1 = (size_t)(m0 + ((c1 >> 6) * 16) + (c1 & 15)) * D_ + (((c1 >> 4) & 3) * 8);
    const size_t aoff2 = (size_t)(m0 + ((c2 >> 6) * 16) + (c2 & 15)) * D_ + (((c2 >> 4) & 3) * 8);
    const size_t boff1 = (size_t)(n0 + ((c1 >> 6) * 16) + (c1 & 15)) * D_ + (((c1 >> 4) & 3) * 8);
    const size_t boff2 = (size_t)(n0 + ((c2 >> 6) * 16) + (c2 & 15)) * D_ + (((c2 >> 4) & 3) * 8);
    const int so1 = w * 1024;        // wave-uniform LDS element offsets
    const int so2 = w * 1024 + 512;

    f32x4 acc[4][4];
    #pragma unroll
    for (int i = 0; i < 4; ++i)
        #pragma unroll
        for (int j = 0; j < 4; ++j)
            acc[i][j] = (f32x4){0.f, 0.f, 0.f, 0.f};

    #define STAGE_Q(t, bi) do {                                     \
        const size_t kq = (size_t)(t) * 32;                         \
        __bf16* Ad = As + (bi) * 4096;                              \
        __bf16* Bd = Bs + (bi) * 4096;                              \
        GLDS(Ap + aoff1 + kq, Ad + so1);                            \
        GLDS(Ap + aoff2 + kq, Ad + so2);                            \
        GLDS(Bp + boff1 + kq, Bd + so1);                            \
        GLDS(Bp + boff2 + kq, Bd + so2);                            \
    } while (0)

    STAGE_Q(0, 0);
    STAGE_Q(1, 1);

    int rb = 0;
    for (int t = 0; t < 32; ++t) {
        // 4 GLDS per tile per wave: vmcnt(4) keeps tile t+1 in flight,
        // guarantees tile t landed. Last iteration drains fully.
        if (t < 31) asm volatile("s_waitcnt vmcnt(4)" ::: "memory");
        else        asm volatile("s_waitcnt vmcnt(0)" ::: "memory");
        __builtin_amdgcn_s_barrier();
        asm volatile("" ::: "memory");   // fence: no ds_read hoists above barrier

        if (t < 30) {
            int wb = rb + 2; if (wb >= 3) wb -= 3;
            STAGE_Q(t + 2, wb);
        }

        const __bf16* Ar = As + rb * 4096;
        const __bf16* Br = Bs + rb * 4096;
        bf16x8 af[4], bfv[4];
        #pragma unroll
        for (int i = 0; i < 4; ++i) {
            af[i]  = *(const bf16x8*)(Ar + ((wr * 4 + i) * 64 + quad * 16 + l15) * 8);
            bfv[i] = *(const bf16x8*)(Br + ((wc * 4 + i) * 64 + quad * 16 + l15) * 8);
        }
        #pragma unroll
        for (int mt = 0; mt < 4; ++mt)
            #pragma unroll
            for (int nt = 0; nt < 4; ++nt)
                acc[mt][nt] = MFMA(af[mt], bfv[nt], acc[mt][nt]);

        rb = rb + 1; if (rb == 3) rb = 0;
    }
    #undef STAGE_Q

    if (!VT) {
        const float* bias = (z == 0) ? bq : bk;
        float bvv[4];
        #pragma unroll
        for (int nt = 0; nt < 4; ++nt)
            bvv[nt] = bias[n0 + wc * 64 + nt * 16 + l15];
        __bf16* C = qk_out + (size_t)z * M_ * D_;
        #pragma unroll
        for (int mt = 0; mt < 4; ++mt) {
            #pragma unroll
            for (int r = 0; r < 4; ++r) {
                const int row = m0 + wr * 64 + mt * 16 + quad * 4 + r;
                #pragma unroll
                for (int nt = 0; nt < 4; ++nt) {
                    const int col = n0 + wc * 64 + nt * 16 + l15;
                    const size_t idx = (((size_t)(row >> 10) * H_ + (col >> 6)) * N_
                                        + (row & 1023)) * DH + (col & 63);
                    C[idx] = (__bf16)(acc[mt][nt][r] + bvv[nt]);
                }
            }
        }
    } else {
        // D[e][m] = V^T; write vT[B,H,Dh,N]; bias bv[e=row]  [verified R10]
        #pragma unroll
        for (int mt = 0; mt < 4; ++mt) {
            #pragma unroll
            for (int r = 0; r < 4; ++r) {
                const int row = m0 + wr * 64 + mt * 16 + quad * 4 + r;   // e
                const float brow = bv[row];
                #pragma unroll
                for (int nt = 0; nt < 4; ++nt) {
                    const int col = n0 + wc * 64 + nt * 16 + l15;        // m
                    const size_t idx = (((size_t)(col >> 10) * H_ + (row >> 6)) * DH
                                        + (row & 63)) * N_ + (col & 1023);
                    vT[idx] = (__bf16)(acc[mt][nt][r] + brow);
                }
            }
        }
    }
}

// ---------------------------------------------------------------------------
// Final projection GEMM — R11: same 3-deep ring / counted-vmcnt transform
// applied to R10's 64x128 MODE0 path. 3 GLDS per tile per wave -> vmcnt(3).
// LDS 36KB (4 blocks/CU capacity; 512-block grid = 2 resident/CU).
// ---------------------------------------------------------------------------
__global__ __launch_bounds__(256, 4) void gemm_out(
    const __bf16* __restrict__ A0, const __bf16* __restrict__ Wb,
    const float* __restrict__ b0, float* __restrict__ Cb)
{
    __shared__ __bf16 As[3 * 2048];   // 3 x 64x32  (12KB)
    __shared__ __bf16 Bs[3 * 4096];   // 3 x 128x32 (24KB)

    const int tid  = threadIdx.x;
    const int w    = tid >> 6;
    const int lane = tid & 63;
    const int quad = lane >> 4;
    const int l15  = lane & 15;
    const int wr   = w >> 1, wc = w & 1;

    const int m0 = blockIdx.y * 64;
    const int n0 = blockIdx.x * 128;

    const int Tt = tid >> 6, ko = (tid >> 4) & 3, l = tid & 15;
    const size_t aoff  = (size_t)(m0 + Tt * 16 + l) * D_ + ko * 8;
    const size_t boff1 = (size_t)(n0 + Tt * 16 + l) * D_ + ko * 8;
    const size_t boff2 = boff1 + (size_t)64 * D_;

    f32x4 acc[2][4];
    #pragma unroll
    for (int i = 0; i < 2; ++i)
        #pragma unroll
        for (int j = 0; j < 4; ++j)
            acc[i][j] = (f32x4){0.f, 0.f, 0.f, 0.f};

    #define STAGE_O(t, bi) do {                                     \
        const size_t kq = (size_t)(t) * 32;                         \
        GLDS(A0 + aoff  + kq, As + (bi) * 2048 + w * 512);          \
        GLDS(Wb + boff1 + kq, Bs + (bi) * 4096 + w * 512);          \
        GLDS(Wb + boff2 + kq, Bs + (bi) * 4096 + 2048 + w * 512);   \
    } while (0)

    STAGE_O(0, 0);
    STAGE_O(1, 1);

    int rb = 0;
    for (int t = 0; t < 32; ++t) {
        if (t < 31) asm volatile("s_waitcnt vmcnt(3)" ::: "memory");
        else        asm volatile("s_waitcnt vmcnt(0)" ::: "memory");
        __builtin_amdgcn_s_barrier();
        asm volatile("" ::: "memory");

        if (t < 30) {
            int wb = rb + 2; if (wb >= 3) wb -= 3;
            STAGE_O(t + 2, wb);
        }

        const __bf16* Ar = As + rb * 2048;
        const __bf16* Br = Bs + rb * 4096;
        bf16x8 af[2], bfv[4];
        #pragma unroll
        for (int mt = 0; mt < 2; ++mt)
            af[mt] = *(const bf16x8*)(Ar + (((wr * 2 + mt) * 4 + quad) * 16 + l15) * 8);
        #pragma unroll
        for (int nt = 0; nt < 4; ++nt)
            bfv[nt] = *(const bf16x8*)(Br + (((wc * 4 + nt) * 4 + quad) * 16 + l15) * 8);
        #pragma unroll
        for (int mt = 0; mt < 2; ++mt)
            #pragma unroll
            for (int nt = 0; nt < 4; ++nt)
                acc[mt][nt] = MFMA(af[mt], bfv[nt], acc[mt][nt]);

        rb = rb + 1; if (rb == 3) rb = 0;
    }
    #undef STAGE_O

    float bvv[4];
    #pragma unroll
    for (int nt = 0; nt < 4; ++nt)
        bvv[nt] = b0[n0 + wc * 64 + nt * 16 + l15];
    #pragma unroll
    for (int mt = 0; mt < 2; ++mt) {
        #pragma unroll
        for (int r = 0; r < 4; ++r) {
            const int row = m0 + (wr * 2 + mt) * 16 + quad * 4 + r;
            #pragma unroll
            for (int nt = 0; nt < 4; ++nt) {
                const int col = n0 + wc * 64 + nt * 16 + l15;
                Cb[(size_t)row * D_ + col] = acc[mt][nt][r] + bvv[nt];
            }
        }
    }
}

// ---------------------------------------------------------------------------
// MFMA flash attention v5 — [verified R8-R10, byte-identical]. K/V staged
// into LDS in fragment order via global_load_lds; ds_read_b128 frag reads;
// single-pass exp2 softmax; per-wave P LDS round-trip.
// ---------------------------------------------------------------------------
#define SP  68
#define SC2 0.04508422f   // (1/32) * log2(e)

__global__ __launch_bounds__(256, 4) void attn_mfma(
    const __bf16* __restrict__ qh, const __bf16* __restrict__ kh,
    const __bf16* __restrict__ vT, __bf16* __restrict__ ob)
{
    __shared__ __bf16 Ks[4096];
    __shared__ __bf16 Vs[4096];
    __shared__ float  Ps[4][16 * SP];

    const int tid  = threadIdx.x;
    const int w    = tid >> 6;
    const int lane = tid & 63;
    const int quad = lane >> 4;
    const int l15  = lane & 15;

    const int bh = blockIdx.x & 63;
    const int qt = blockIdx.x >> 6;
    const int b  = bh >> 4;
    const int h  = bh & 15;

    const __bf16* qp = qh + ((size_t)(b * H_ + h) * N_ + qt * 64 + w * 16 + l15) * DH + quad * 8;
    const bf16x8 qf0 = *(const bf16x8*)(qp);
    const bf16x8 qf1 = *(const bf16x8*)(qp + 32);

    const int c1 = tid, c2 = tid + 256;
    const int nt1 = c1 >> 7, ko1 = (c1 >> 4) & 7, l1 = c1 & 15;
    const int nt2 = c2 >> 7, ko2 = (c2 >> 4) & 7, l2 = c2 & 15;
    const __bf16* khead = kh + (size_t)(b * H_ + h) * N_ * DH;
    const __bf16* vhead = vT + (size_t)(b * H_ + h) * DH * N_;
    const size_t koff1 = (size_t)(nt1 * 16 + l1) * DH + ko1 * 8;
    const size_t koff2 = (size_t)(nt2 * 16 + l2) * DH + ko2 * 8;
    const size_t voff1 = (size_t)(nt1 * 16 + l1) * N_ + ko1 * 8;
    const size_t voff2 = (size_t)(nt2 * 16 + l2) * N_ + ko2 * 8;
    __bf16* ksdst1 = Ks + w * 512;
    __bf16* ksdst2 = Ks + 2048 + w * 512;
    __bf16* vsdst1 = Vs + w * 512;
    __bf16* vsdst2 = Vs + 2048 + w * 512;

    float psum[4] = {0.f, 0.f, 0.f, 0.f};
    f32x4 Ov[4];
    #pragma unroll
    for (int nt = 0; nt < 4; ++nt) Ov[nt] = (f32x4){0.f, 0.f, 0.f, 0.f};

    for (int kt = 0; kt < 16; ++kt) {
        GLDS(khead + (size_t)kt * 64 * DH + koff1, ksdst1);
        GLDS(khead + (size_t)kt * 64 * DH + koff2, ksdst2);
        GLDS(vhead + (size_t)kt * 64 + voff1, vsdst1);
        GLDS(vhead + (size_t)kt * 64 + voff2, vsdst2);
        __syncthreads();

        f32x4 sa[4];
        #pragma unroll
        for (int nt = 0; nt < 4; ++nt) {
            const bf16x8 kf0 = *(const bf16x8*)(Ks + (nt * 128 + quad * 16 + l15) * 8);
            const bf16x8 kf1 = *(const bf16x8*)(Ks + (nt * 128 + (quad + 4) * 16 + l15) * 8);
            sa[nt] = (f32x4){0.f, 0.f, 0.f, 0.f};
            sa[nt] = MFMA(qf0, kf0, sa[nt]);
            sa[nt] = MFMA(qf1, kf1, sa[nt]);
        }

        #pragma unroll
        for (int nt = 0; nt < 4; ++nt) {
            #pragma unroll
            for (int r = 0; r < 4; ++r) {
                const float p = __builtin_exp2f(sa[nt][r] * SC2);
                psum[r] += p;
                Ps[w][(quad * 4 + r) * SP + nt * 16 + l15] = p;
            }
        }

        #pragma unroll
        for (int kw = 0; kw < 2; ++kw) {
            const f32x4 pa = *(const f32x4*)&Ps[w][l15 * SP + kw * 32 + quad * 8];
            const f32x4 pb = *(const f32x4*)&Ps[w][l15 * SP + kw * 32 + quad * 8 + 4];
            bf16x8 pf;
            #pragma unroll
            for (int j = 0; j < 4; ++j) { pf[j] = (__bf16)pa[j]; pf[4 + j] = (__bf16)pb[j]; }
            #pragma unroll
            for (int nt = 0; nt < 4; ++nt) {
                const bf16x8 vf = *(const bf16x8*)(Vs + (nt * 128 + (kw * 4 + quad) * 16 + l15) * 8);
                Ov[nt] = MFMA(pf, vf, Ov[nt]);
            }
        }
        __syncthreads();
    }

    float lrow[4];
    #pragma unroll
    for (int r = 0; r < 4; ++r) {
        float lt = psum[r];
        lt += __shfl_xor(lt, 1);
        lt += __shfl_xor(lt, 2);
        lt += __shfl_xor(lt, 4);
        lt += __shfl_xor(lt, 8);
        lrow[r] = lt;
    }

    #pragma unroll
    for (int r = 0; r < 4; ++r) {
        const float inv = 1.0f / lrow[r];
        const int row = qt * 64 + w * 16 + quad * 4 + r;
        __bf16* op = ob + ((size_t)(b * H_ + h) * N_ + row) * DH + l15;
        #pragma unroll
        for (int nt = 0; nt < 4; ++nt)
            op[nt * 16] = (__bf16)(Ov[nt][r] * inv);
    }
}

// ---------------------------------------------------------------------------
extern "C" void kernel_launch(void* const* d_in, const int* in_sizes, int n_in,
                              void* d_out, int out_size, void* d_ws, size_t ws_size,
                              hipStream_t stream) {
    const float* x  = (const float*)d_in[0];
    const float* Wq = (const float*)d_in[1];
    const float* bq = (const float*)d_in[2];
    const float* Wk = (const float*)d_in[3];
    const float* bk = (const float*)d_in[4];
    const float* Wv = (const float*)d_in[5];
    const float* bv = (const float*)d_in[6];
    const float* Wc = (const float*)d_in[7];
    const float* bc = (const float*)d_in[8];
    float* out = (float*)d_out;

    // ws layout (48 MB):
    //   [ 0, 8MB): xb (bf16 4Mi) -- dead after QKV GEMM, reused as obf
    //   [ 8,14MB): wqkvb  [14,16MB): wcb
    //   [16,40MB): qkvb (q,k slabs [B,H,N,Dh]; 3rd slab unused)
    //   [40,48MB): vT [B,H,Dh,N] (written directly by gemm_qkv z=2)
    char* base = (char*)d_ws;
    __bf16* xb    = (__bf16*)(base);
    __bf16* wqkvb = (__bf16*)(base + (size_t)8  * 1048576);
    __bf16* wcb   = (__bf16*)(base + (size_t)14 * 1048576);
    __bf16* qkvb  = (__bf16*)(base + (size_t)16 * 1048576);
    __bf16* vTb   = (__bf16*)(base + (size_t)40 * 1048576);
    __bf16* obf   = (__bf16*)(base);   // overwrites xb after attn

    __bf16* qhb = qkvb;
    __bf16* khb = qkvb + (size_t)M_ * D_;

    convert_k<<<dim3(4096), dim3(256), 0, stream>>>(
        x, Wq, Wk, Wv, Wc, xb, wqkvb, wcb);

    gemm_qkv<<<dim3(8, 32, 3), dim3(256), 0, stream>>>(
        xb, wqkvb, bq, bk, bv, qkvb, vTb);

    attn_mfma<<<dim3(1024), dim3(256), 0, stream>>>(qhb, khb, vTb, obf);

    gemm_out<<<dim3(8, 64, 1), dim3(256), 0, stream>>>(obf, wcb, bc, out);
}

// Round 2
// 194.034 us; speedup vs baseline: 1.0800x; 1.0800x over previous
//
#include <hip/hip_runtime.h>
#include <cstddef>
#include <cstdint>

#define B_  4
#define N_  1024
#define D_  1024
#define H_  16
#define DH  64
#define M_  4096   // B_*N_

typedef __attribute__((ext_vector_type(4))) float   f32x4;
typedef __attribute__((ext_vector_type(8))) __bf16  bf16x8;

#define MFMA(a, b, c) __builtin_amdgcn_mfma_f32_16x16x32_bf16((a), (b), (c), 0, 0, 0)
#define GLDS(gp, lp) __builtin_amdgcn_global_load_lds( \
    (__attribute__((address_space(1))) void*)(gp),     \
    (__attribute__((address_space(3))) void*)(lp), 16, 0, 0)

// ---------------------------------------------------------------------------
// convert: fp32 -> bf16 for x (4Mi) and Wq/Wk/Wv/Wc (4x1Mi). [verified R3]
// ---------------------------------------------------------------------------
__global__ __launch_bounds__(256) void convert_k(
    const float* __restrict__ x,  const float* __restrict__ Wq,
    const float* __restrict__ Wk, const float* __restrict__ Wv,
    const float* __restrict__ Wc,
    __bf16* __restrict__ xb, __bf16* __restrict__ wqkvb,
    __bf16* __restrict__ wcb)
{
    const unsigned u = blockIdx.x * 256u + threadIdx.x;
    const unsigned e = u * 8u;
    const float* src;
    __bf16* dst;
    if (e < 4194304u) { src = x + e; dst = xb + e; }
    else {
        const unsigned t2 = e - 4194304u;
        const unsigned wsel = t2 >> 20;
        const unsigned wo = t2 & 1048575u;
        src = (wsel == 0 ? Wq : wsel == 1 ? Wk : wsel == 2 ? Wv : Wc) + wo;
        dst = (wsel < 3 ? wqkvb + (size_t)wsel * 1048576u : wcb) + wo;
    }
    const float4 f0 = *(const float4*)(src);
    const float4 f1 = *(const float4*)(src + 4);
    bf16x8 r;
    r[0] = (__bf16)f0.x; r[1] = (__bf16)f0.y; r[2] = (__bf16)f0.z; r[3] = (__bf16)f0.w;
    r[4] = (__bf16)f1.x; r[5] = (__bf16)f1.y; r[6] = (__bf16)f1.z; r[7] = (__bf16)f1.w;
    *(bf16x8*)dst = r;
}

// ---------------------------------------------------------------------------
// QKV GEMM — R12: 8-phase 256^2 template (T3+T4+T5), fused QKV in 192 blocks.
//   bid <  128: QK part, C[4096 x 2048] = xb . [Wq;Wk]^T, heads epilogue.
//   bid >= 128: V part (swapped operands, [verified R10]): D[e][m] = Wv.xb^T
//               written directly as vT[B,H,Dh,N].
// Geometry: BM=BN=256, BK=64, 8 waves (2Mx4N), per-wave 128x64 = acc[8][4],
// 64 MFMA/K-tile/wave, 16 K-tiles. LDS = 128KB ring: A,B each 4 half-tile
// slots (16KB = 16 fragments x 1KB), FRAGMENT-ORDERED (0 bank conflicts by
// construction [measured R0-R11], glds-compatible: 1 wave-load = 1 fragment).
// Schedule per K-tile t (4 phases, 2 barriers each; boundary vmcnt(4)):
//   boundary: vmcnt(4) [tail: vmcnt(0)]; s_barrier
//   ph0: stage A0(t+1); read 8 B-frags + 4 A-frags; bar; lgkm0; prio1; 16 MFMA; prio0; bar
//   ph1: stage A1(t+1); read 4 A-frags; ...
//   ph2: stage B0(t+2); read 4 A-frags; ...
//   ph3: stage B1(t+2); read 4 A-frags; ... (end barrier = next boundary)
// Ledger [checked]: at boundary t, pending = {B(t) g(t-2).ph2/3, A(t)
// g(t-1).ph0/1, B(t+1) g(t-1).ph2/3}; vmcnt(4) completes A(t),B(t), leaves
// B(t+1) x 4 loads in flight. Slot-overwrite safety: A(t+1) slots dead since
// g(t-1).ph3 reads (< boundary barrier); B(t+2) slots dead since ph0 lgkm
// (< ph0-end barrier < ph2). Prologue order B(0),A(0),B(1) matches ledger.
// ---------------------------------------------------------------------------
__global__ __launch_bounds__(512, 2) void gemm_qkv256(
    const __bf16* __restrict__ xb, const __bf16* __restrict__ Wb,
    const float* __restrict__ bq, const float* __restrict__ bk,
    const float* __restrict__ bv,
    __bf16* __restrict__ qk_out, __bf16* __restrict__ vT)
{
    __shared__ __bf16 ring[65536];   // [A: 4 x 8192][B: 4 x 8192] = 128KB

    const int tid  = threadIdx.x;
    const int w    = tid >> 6;        // 0..7
    const int lane = tid & 63;
    const int quad = lane >> 4;
    const int l15  = lane & 15;
    const int wr   = w >> 2;          // 0..1  (M half)
    const int wc   = w & 3;           // 0..3  (N quarter)

    const int bid = blockIdx.x;
    const bool VT = (bid >= 128);
    int m0, n0;
    const __bf16 *Ap, *Bp;
    if (!VT) { m0 = (bid >> 3) * 256; n0 = (bid & 7) * 256; Ap = xb; Bp = Wb; }
    else {
        const int v = bid - 128;
        m0 = (v & 3) * 256;           // over e (Wv rows)
        n0 = (v >> 2) * 256;          // over m (xb rows)
        Ap = Wb + (size_t)2 * D_ * D_; Bp = xb;
    }

    // staging: wave w stages m-frag w of each half; load j covers kf=j.
    // lane -> row (lane&15), k-octet (lane>>4)*8. One glds = one fragment.
    const size_t sgl = (size_t)(w * 16 + l15) * D_ + quad * 8;
    const __bf16* Asrc = Ap + (size_t)m0 * D_ + sgl;
    const __bf16* Bsrc = Bp + (size_t)n0 * D_ + sgl;
    __bf16* const ringA = ring;
    __bf16* const ringB = ring + 32768;
    const int sdst = w * 1024;        // frag (w, j) dst = slot + w*1024 + j*512

#define STG_A(tt, h) do {                                               \
    const __bf16* s_ = Asrc + (size_t)(h) * 128 * D_ + (tt) * 64;       \
    __bf16* d_ = ringA + ((((tt) & 1) * 2 + (h)) * 8192) + sdst;        \
    GLDS(s_, d_); GLDS(s_ + 32, d_ + 512); } while (0)
#define STG_B(tt, h) do {                                               \
    const __bf16* s_ = Bsrc + (size_t)(h) * 128 * D_ + (tt) * 64;       \
    __bf16* d_ = ringB + ((((tt) & 1) * 2 + (h)) * 8192) + sdst;        \
    GLDS(s_, d_); GLDS(s_ + 32, d_ + 512); } while (0)

    f32x4 acc[8][4];
    #pragma unroll
    for (int i = 0; i < 8; ++i)
        #pragma unroll
        for (int j = 0; j < 4; ++j)
            acc[i][j] = (f32x4){0.f, 0.f, 0.f, 0.f};

    // prologue: order matters for the vmcnt ledger (oldest = B(0))
    STG_B(0, 0); STG_B(0, 1);
    STG_A(0, 0); STG_A(0, 1);
    STG_B(1, 0); STG_B(1, 1);

    const int rdo = lane * 8;         // frag-read: lane i -> chunk i (16B)

#define READ_A(q)                                                       \
    afr[0][0] = *(const bf16x8*)(Asl + ((2*(q)  )*2 + 0)*512);          \
    afr[0][1] = *(const bf16x8*)(Asl + ((2*(q)  )*2 + 1)*512);          \
    afr[1][0] = *(const bf16x8*)(Asl + ((2*(q)+1)*2 + 0)*512);          \
    afr[1][1] = *(const bf16x8*)(Asl + ((2*(q)+1)*2 + 1)*512);

#define PHASE_MFMA(q)                                                   \
    __builtin_amdgcn_s_barrier();                                       \
    asm volatile("s_waitcnt lgkmcnt(0)" ::: "memory");                  \
    __builtin_amdgcn_s_setprio(1);                                      \
    _Pragma("unroll")                                                   \
    for (int i = 0; i < 2; ++i)                                         \
      _Pragma("unroll")                                                 \
      for (int nt = 0; nt < 4; ++nt) {                                  \
        acc[2*(q)+i][nt] = MFMA(afr[i][0], bfr[nt][0], acc[2*(q)+i][nt]); \
        acc[2*(q)+i][nt] = MFMA(afr[i][1], bfr[nt][1], acc[2*(q)+i][nt]); \
      }                                                                 \
    __builtin_amdgcn_s_setprio(0);

    for (int t = 0; t < 16; ++t) {
        if (t < 15) asm volatile("s_waitcnt vmcnt(4)" ::: "memory");
        else        asm volatile("s_waitcnt vmcnt(0)" ::: "memory");
        __builtin_amdgcn_s_barrier();

        const __bf16* Asl = ringA + ((t & 1) * 2 + wr) * 8192 + rdo;
        const __bf16* Bsl = ringB + ((t & 1) * 2 + (wc >> 1)) * 8192
                                  + (wc & 1) * 4096 + rdo;
        bf16x8 afr[2][2], bfr[4][2];

        // ---- phase 0: B-frags (held all group) + A quadrant 0 ----
        if (t < 15) STG_A(t + 1, 0);
        #pragma unroll
        for (int nt = 0; nt < 4; ++nt) {
            bfr[nt][0] = *(const bf16x8*)(Bsl + (nt * 2 + 0) * 512);
            bfr[nt][1] = *(const bf16x8*)(Bsl + (nt * 2 + 1) * 512);
        }
        READ_A(0)
        PHASE_MFMA(0)
        __builtin_amdgcn_s_barrier();

        // ---- phase 1 ----
        if (t < 15) STG_A(t + 1, 1);
        READ_A(1)
        PHASE_MFMA(1)
        __builtin_amdgcn_s_barrier();

        // ---- phase 2 ----
        if (t < 14) STG_B(t + 2, 0);
        READ_A(2)
        PHASE_MFMA(2)
        __builtin_amdgcn_s_barrier();

        // ---- phase 3 (end barrier = next boundary) ----
        if (t < 14) STG_B(t + 2, 1);
        READ_A(3)
        PHASE_MFMA(3)
    }
#undef STG_A
#undef STG_B
#undef READ_A
#undef PHASE_MFMA

    if (!VT) {
        const int zq = n0 >> 10;                  // 0:Q 1:K (256 | 1024 -> const/block)
        const float* bias = zq ? bk : bq;
        const int nb = (n0 & 1023) + wc * 64;     // within-slab col base
        float bvv[4];
        #pragma unroll
        for (int nt = 0; nt < 4; ++nt) bvv[nt] = bias[nb + nt * 16 + l15];
        __bf16* C = qk_out + (size_t)zq * M_ * D_;
        #pragma unroll
        for (int mt = 0; mt < 8; ++mt) {
            #pragma unroll
            for (int r = 0; r < 4; ++r) {
                const int row = m0 + wr * 128 + mt * 16 + quad * 4 + r;
                #pragma unroll
                for (int nt = 0; nt < 4; ++nt) {
                    const int col = nb + nt * 16 + l15;      // 0..1023
                    const size_t idx = (((size_t)(row >> 10) * H_ + (col >> 6)) * N_
                                        + (row & 1023)) * DH + (col & 63);
                    C[idx] = (__bf16)(acc[mt][nt][r] + bvv[nt]);
                }
            }
        }
    } else {
        // D[e][m] = V^T -> vT[B,H,Dh,N]; bias bv[e=row]  [mapping verified R10]
        #pragma unroll
        for (int mt = 0; mt < 8; ++mt) {
            #pragma unroll
            for (int r = 0; r < 4; ++r) {
                const int row = m0 + wr * 128 + mt * 16 + quad * 4 + r;   // e
                const float brow = bv[row];
                #pragma unroll
                for (int nt = 0; nt < 4; ++nt) {
                    const int col = n0 + wc * 64 + nt * 16 + l15;         // m
                    const size_t idx = (((size_t)(col >> 10) * H_ + (row >> 6)) * DH
                                        + (row & 63)) * N_ + (col & 1023);
                    vT[idx] = (__bf16)(acc[mt][nt][r] + brow);
                }
            }
        }
    }
}

// ---------------------------------------------------------------------------
// Final projection GEMM — R10's gemm64 MODE0 path (64x128, BK=32, 512 blocks
// = 2 blocks/CU). [reverted to R10-verified form; R11 ring was neutral]
// ---------------------------------------------------------------------------
__global__ __launch_bounds__(256, 6) void gemm_out(
    const __bf16* __restrict__ A0, const __bf16* __restrict__ Wb,
    const float* __restrict__ b0, float* __restrict__ Cb)
{
    __shared__ __bf16 As[2048];   // 64x32, frag-ordered (4KB)
    __shared__ __bf16 Bs[4096];   // 128x32, frag-ordered (8KB)

    const int tid  = threadIdx.x;
    const int w    = tid >> 6;
    const int lane = tid & 63;
    const int quad = lane >> 4;
    const int l15  = lane & 15;
    const int wr   = w >> 1, wc = w & 1;

    const int m0 = blockIdx.y * 64;
    const int n0 = blockIdx.x * 128;

    const int Tt = tid >> 6, ko = (tid >> 4) & 3, l = tid & 15;
    const size_t aoff  = (size_t)(m0 + Tt * 16 + l) * D_ + ko * 8;
    const size_t boff1 = (size_t)(n0 + Tt * 16 + l) * D_ + ko * 8;
    const size_t boff2 = boff1 + (size_t)64 * D_;
    __bf16* adst  = As + w * 512;
    __bf16* bdst1 = Bs + w * 512;
    __bf16* bdst2 = Bs + 2048 + w * 512;

    f32x4 acc[2][4];
    #pragma unroll
    for (int i = 0; i < 2; ++i)
        #pragma unroll
        for (int j = 0; j < 4; ++j)
            acc[i][j] = (f32x4){0.f, 0.f, 0.f, 0.f};

    for (int k0 = 0; k0 < D_; k0 += 32) {
        GLDS(A0 + aoff  + k0, adst);
        GLDS(Wb + boff1 + k0, bdst1);
        GLDS(Wb + boff2 + k0, bdst2);
        __syncthreads();

        bf16x8 af[2], bf[4];
        #pragma unroll
        for (int mt = 0; mt < 2; ++mt)
            af[mt] = *(const bf16x8*)(As + (((wr * 2 + mt) * 4 + quad) * 16 + l15) * 8);
        #pragma unroll
        for (int nt = 0; nt < 4; ++nt)
            bf[nt] = *(const bf16x8*)(Bs + (((wc * 4 + nt) * 4 + quad) * 16 + l15) * 8);
        #pragma unroll
        for (int mt = 0; mt < 2; ++mt)
            #pragma unroll
            for (int nt = 0; nt < 4; ++nt)
                acc[mt][nt] = MFMA(af[mt], bf[nt], acc[mt][nt]);
        __syncthreads();
    }

    float bvv[4];
    #pragma unroll
    for (int nt = 0; nt < 4; ++nt)
        bvv[nt] = b0[n0 + wc * 64 + nt * 16 + l15];
    #pragma unroll
    for (int mt = 0; mt < 2; ++mt) {
        #pragma unroll
        for (int r = 0; r < 4; ++r) {
            const int row = m0 + (wr * 2 + mt) * 16 + quad * 4 + r;
            #pragma unroll
            for (int nt = 0; nt < 4; ++nt) {
                const int col = n0 + wc * 64 + nt * 16 + l15;
                Cb[(size_t)row * D_ + col] = acc[mt][nt][r] + bvv[nt];
            }
        }
    }
}

// ---------------------------------------------------------------------------
// MFMA flash attention v5 — [verified R8-R10, byte-identical]. K/V staged
// into LDS in fragment order via global_load_lds; ds_read_b128 frag reads;
// single-pass exp2 softmax; per-wave P LDS round-trip.
// ---------------------------------------------------------------------------
#define SP  68
#define SC2 0.04508422f   // (1/32) * log2(e)

__global__ __launch_bounds__(256, 4) void attn_mfma(
    const __bf16* __restrict__ qh, const __bf16* __restrict__ kh,
    const __bf16* __restrict__ vT, __bf16* __restrict__ ob)
{
    __shared__ __bf16 Ks[4096];
    __shared__ __bf16 Vs[4096];
    __shared__ float  Ps[4][16 * SP];

    const int tid  = threadIdx.x;
    const int w    = tid >> 6;
    const int lane = tid & 63;
    const int quad = lane >> 4;
    const int l15  = lane & 15;

    const int bh = blockIdx.x & 63;
    const int qt = blockIdx.x >> 6;
    const int b  = bh >> 4;
    const int h  = bh & 15;

    const __bf16* qp = qh + ((size_t)(b * H_ + h) * N_ + qt * 64 + w * 16 + l15) * DH + quad * 8;
    const bf16x8 qf0 = *(const bf16x8*)(qp);
    const bf16x8 qf1 = *(const bf16x8*)(qp + 32);

    const int c1 = tid, c2 = tid + 256;
    const int nt1 = c1 >> 7, ko1 = (c1 >> 4) & 7, l1 = c1 & 15;
    const int nt2 = c2 >> 7, ko2 = (c2 >> 4) & 7, l2 = c2 & 15;
    const __bf16* khead = kh + (size_t)(b * H_ + h) * N_ * DH;
    const __bf16* vhead = vT + (size_t)(b * H_ + h) * DH * N_;
    const size_t koff1 = (size_t)(nt1 * 16 + l1) * DH + ko1 * 8;
    const size_t koff2 = (size_t)(nt2 * 16 + l2) * DH + ko2 * 8;
    const size_t voff1 = (size_t)(nt1 * 16 + l1) * N_ + ko1 * 8;
    const size_t voff2 = (size_t)(nt2 * 16 + l2) * N_ + ko2 * 8;
    __bf16* ksdst1 = Ks + w * 512;
    __bf16* ksdst2 = Ks + 2048 + w * 512;
    __bf16* vsdst1 = Vs + w * 512;
    __bf16* vsdst2 = Vs + 2048 + w * 512;

    float psum[4] = {0.f, 0.f, 0.f, 0.f};
    f32x4 Ov[4];
    #pragma unroll
    for (int nt = 0; nt < 4; ++nt) Ov[nt] = (f32x4){0.f, 0.f, 0.f, 0.f};

    for (int kt = 0; kt < 16; ++kt) {
        GLDS(khead + (size_t)kt * 64 * DH + koff1, ksdst1);
        GLDS(khead + (size_t)kt * 64 * DH + koff2, ksdst2);
        GLDS(vhead + (size_t)kt * 64 + voff1, vsdst1);
        GLDS(vhead + (size_t)kt * 64 + voff2, vsdst2);
        __syncthreads();

        f32x4 sa[4];
        #pragma unroll
        for (int nt = 0; nt < 4; ++nt) {
            const bf16x8 kf0 = *(const bf16x8*)(Ks + (nt * 128 + quad * 16 + l15) * 8);
            const bf16x8 kf1 = *(const bf16x8*)(Ks + (nt * 128 + (quad + 4) * 16 + l15) * 8);
            sa[nt] = (f32x4){0.f, 0.f, 0.f, 0.f};
            sa[nt] = MFMA(qf0, kf0, sa[nt]);
            sa[nt] = MFMA(qf1, kf1, sa[nt]);
        }

        #pragma unroll
        for (int nt = 0; nt < 4; ++nt) {
            #pragma unroll
            for (int r = 0; r < 4; ++r) {
                const float p = __builtin_exp2f(sa[nt][r] * SC2);
                psum[r] += p;
                Ps[w][(quad * 4 + r) * SP + nt * 16 + l15] = p;
            }
        }

        #pragma unroll
        for (int kw = 0; kw < 2; ++kw) {
            const f32x4 pa = *(const f32x4*)&Ps[w][l15 * SP + kw * 32 + quad * 8];
            const f32x4 pb = *(const f32x4*)&Ps[w][l15 * SP + kw * 32 + quad * 8 + 4];
            bf16x8 pf;
            #pragma unroll
            for (int j = 0; j < 4; ++j) { pf[j] = (__bf16)pa[j]; pf[4 + j] = (__bf16)pb[j]; }
            #pragma unroll
            for (int nt = 0; nt < 4; ++nt) {
                const bf16x8 vf = *(const bf16x8*)(Vs + (nt * 128 + (kw * 4 + quad) * 16 + l15) * 8);
                Ov[nt] = MFMA(pf, vf, Ov[nt]);
            }
        }
        __syncthreads();
    }

    float lrow[4];
    #pragma unroll
    for (int r = 0; r < 4; ++r) {
        float lt = psum[r];
        lt += __shfl_xor(lt, 1);
        lt += __shfl_xor(lt, 2);
        lt += __shfl_xor(lt, 4);
        lt += __shfl_xor(lt, 8);
        lrow[r] = lt;
    }

    #pragma unroll
    for (int r = 0; r < 4; ++r) {
        const float inv = 1.0f / lrow[r];
        const int row = qt * 64 + w * 16 + quad * 4 + r;
        __bf16* op = ob + ((size_t)(b * H_ + h) * N_ + row) * DH + l15;
        #pragma unroll
        for (int nt = 0; nt < 4; ++nt)
            op[nt * 16] = (__bf16)(Ov[nt][r] * inv);
    }
}

// ---------------------------------------------------------------------------
extern "C" void kernel_launch(void* const* d_in, const int* in_sizes, int n_in,
                              void* d_out, int out_size, void* d_ws, size_t ws_size,
                              hipStream_t stream) {
    const float* x  = (const float*)d_in[0];
    const float* Wq = (const float*)d_in[1];
    const float* bq = (const float*)d_in[2];
    const float* Wk = (const float*)d_in[3];
    const float* bk = (const float*)d_in[4];
    const float* Wv = (const float*)d_in[5];
    const float* bv = (const float*)d_in[6];
    const float* Wc = (const float*)d_in[7];
    const float* bc = (const float*)d_in[8];
    float* out = (float*)d_out;

    // ws layout (48 MB):
    //   [ 0, 8MB): xb (bf16 4Mi) -- dead after QKV GEMM, reused as obf
    //   [ 8,14MB): wqkvb  [14,16MB): wcb
    //   [16,40MB): qkvb (q,k slabs [B,H,N,Dh]; 3rd slab unused)
    //   [40,48MB): vT [B,H,Dh,N] (written directly by gemm_qkv256 V-part)
    char* base = (char*)d_ws;
    __bf16* xb    = (__bf16*)(base);
    __bf16* wqkvb = (__bf16*)(base + (size_t)8  * 1048576);
    __bf16* wcb   = (__bf16*)(base + (size_t)14 * 1048576);
    __bf16* qkvb  = (__bf16*)(base + (size_t)16 * 1048576);
    __bf16* vTb   = (__bf16*)(base + (size_t)40 * 1048576);
    __bf16* obf   = (__bf16*)(base);   // overwrites xb after attn

    __bf16* qhb = qkvb;
    __bf16* khb = qkvb + (size_t)M_ * D_;

    convert_k<<<dim3(4096), dim3(256), 0, stream>>>(
        x, Wq, Wk, Wv, Wc, xb, wqkvb, wcb);

    gemm_qkv256<<<dim3(192), dim3(512), 0, stream>>>(
        xb, wqkvb, bq, bk, bv, qkvb, vTb);

    attn_mfma<<<dim3(1024), dim3(256), 0, stream>>>(qhb, khb, vTb, obf);

    gemm_out<<<dim3(8, 64, 1), dim3(256), 0, stream>>>(obf, wcb, bc, out);
}